// Round 4
// baseline (243.675 us; speedup 1.0000x reference)
//
#include <hip/hip_runtime.h>
#include <hip/hip_bf16.h>
#include <stdint.h>

// Problem constants
#define BB 8
#define NN 4096
#define NE 8190
#define VV 256
#define HH 128
#define WPR 64      // u64 words per bitmap row (4096 bits)
#define MAXD 32     // unique-degree capacity (Poisson lambda~2, max ~12)
#define SLICES 16   // pool accumulation slices per batch
#define RPB 8       // rows per block in fused kernel
#define NBLK_FUSED (BB * NN / RPB)   // 4096

// ---------------------------------------------------------------------------
// K1 (specialized blocks):
//  blocks [0,256): bitmap-dedup edge scatter -> unique out/in lists + degrees
//  blocks [256,384): embW1[v,o] = sum_k emb[v,k]*w1[o,k]  (2 v-rows/block)
__global__ void k_scatter_embw1(const int* __restrict__ edges,
                                const float* __restrict__ emb,
                                const float* __restrict__ w1,
                                unsigned long long* __restrict__ bits,
                                int2* __restrict__ deg,
                                unsigned short* __restrict__ outl,
                                unsigned short* __restrict__ inl,
                                float* __restrict__ embw1) {
    int blk = blockIdx.x, t = threadIdx.x;
    if (blk < 256) {
        int idx = blk * 256 + t;
        if (idx >= BB * NE) return;
        int b = idx / NE;
        int src = edges[idx * 2 + 0];
        int dst = edges[idx * 2 + 1];
        int row = b * NN + src;
        unsigned long long m = 1ull << (dst & 63);
        unsigned long long old = atomicOr(&bits[(size_t)row * WPR + (dst >> 6)], m);
        if (!(old & m)) {   // first occurrence owns the unique edge
            int po = atomicAdd(&deg[row].x, 1);
            if (po < MAXD) outl[(size_t)row * MAXD + po] = (unsigned short)dst;
            int col = b * NN + dst;
            int pi = atomicAdd(&deg[col].y, 1);
            if (pi < MAXD) inl[(size_t)col * MAXD + pi] = (unsigned short)src;
        }
    } else {
        __shared__ float er[256];
        int v = (blk - 256) * 2 + (t >> 7);
        int o = t & 127;
        er[t] = emb[v * HH + o];
        __syncthreads();
        const float* erow = &er[(t >> 7) * HH];
        float acc = 0.f;
#pragma unroll 8
        for (int k = 0; k < HH; k++) acc += erow[k] * w1[o * HH + k];
        embw1[v * HH + o] = acc;
    }
}

// ---------------------------------------------------------------------------
// K2: fused SpMM + bias + relu + column-weighted mean-pool + (last block only)
//     slice-sum, layer-2 GEMV, L2-normalize.
//     Per row i: dis_i = rsqrt(outdeg_i+1)
//       acc_t = dis_i*embW1[tid_i][t] + sum_{j in out(i)} dis_j*embW1[tid_j][t]
//       h_t   = relu(dis_i*acc_t + b1_t)
//       c_i   = dis_i*(s_i + dis_i),  s_i = sum_{u in in(i)} dis_u
//       psum_t += c_i*h_t
__global__ void __launch_bounds__(128)
k_fused(const int* __restrict__ type_ids,
        const float* __restrict__ embw1,
        const int2* __restrict__ deg,
        const unsigned short* __restrict__ outl,
        const unsigned short* __restrict__ inl,
        const float* __restrict__ b1,
        const float* __restrict__ w2,
        const float* __restrict__ b2,
        float* __restrict__ p,
        int* __restrict__ cnt,
        float* __restrict__ out) {
    __shared__ unsigned short colsO[RPB][MAXD];   // 512 B, staged coalesced
    __shared__ unsigned short colsI[RPB][MAXD];   // 512 B
    __shared__ int2  degsh[RPB];
    __shared__ int   tidsh[RPB];
    __shared__ float djs[MAXD];
    __shared__ int   tjs[MAXD];
    __shared__ float s_sh;
    __shared__ int   lastsh;

    int t = threadIdx.x;
    int blk = blockIdx.x;
    int base = blk * RPB;
    int b = base >> 12;                       // / NN

    // ---- up-front coalesced staging of all RPB rows' metadata ----
    ((unsigned int*)colsO)[t] = ((const unsigned int*)(outl + (size_t)base * MAXD))[t];
    ((unsigned int*)colsI)[t] = ((const unsigned int*)(inl  + (size_t)base * MAXD))[t];
    if (t < RPB) { degsh[t] = deg[base + t]; tidsh[t] = type_ids[base + t]; }
    float b1t = b1[t];
    __syncthreads();

    float psum = 0.f;
    for (int r = 0; r < RPB; r++) {
        int mo = min(degsh[r].x, MAXD);
        int mi = min(degsh[r].y, MAXD);
        if (t < mo) {                          // parallel neighbor-meta gather
            int gj = b * NN + (int)colsO[r][t];
            djs[t] = rsqrtf((float)(deg[gj].x + 1));
            tjs[t] = type_ids[gj];
        }
        float sloc = 0.f;
        if (t < mi) {
            int gu = b * NN + (int)colsI[r][t];
            sloc = rsqrtf((float)(deg[gu].x + 1));
        }
        if (t < 64) {                          // entries live in lanes 0..31
#pragma unroll
            for (int off = 16; off >= 1; off >>= 1)
                sloc += __shfl_down(sloc, off, 32);
            if (t == 0) s_sh = sloc;
        }
        __syncthreads();
        float dis_i = rsqrtf((float)(degsh[r].x + 1));
        float acc = dis_i * embw1[tidsh[r] * HH + t];   // eye (self-loop) term
        for (int q = 0; q < mo; q++)
            acc += djs[q] * embw1[tjs[q] * HH + t];
        float h = fmaxf(dis_i * acc + b1t, 0.f);
        psum += dis_i * (s_sh + dis_i) * h;
        __syncthreads();
    }
    int slice = blk & (SLICES - 1);
    atomicAdd(&p[((size_t)b * SLICES + slice) * HH + t], psum);

    // ---- last-block finalize (release/acquire via threadfence + ticket) ----
    __threadfence();
    if (t == 0) lastsh = atomicAdd(cnt, 1);
    __syncthreads();
    if (lastsh != NBLK_FUSED - 1) return;
    __threadfence();

    __shared__ float pl[BB][HH];               // 4 KB
    __shared__ float red[BB][HH];              // 4 KB
    for (int bb = 0; bb < BB; bb++) {
        float accp = 0.f;
#pragma unroll
        for (int s = 0; s < SLICES; s++)
            accp += p[((size_t)bb * SLICES + s) * HH + t];
        pl[bb][t] = accp * (1.0f / (float)NN);
    }
    __syncthreads();
    float accb[BB];
#pragma unroll
    for (int bb = 0; bb < BB; bb++) accb[bb] = b2[t];
    for (int k = 0; k < HH; k++) {
        float wv = w2[t * HH + k];             // w2 row per thread, L1/L2-hit
#pragma unroll
        for (int bb = 0; bb < BB; bb++) accb[bb] += pl[bb][k] * wv;
    }
#pragma unroll
    for (int bb = 0; bb < BB; bb++) red[bb][t] = accb[bb] * accb[bb];
    __syncthreads();
    for (int stride = 64; stride > 0; stride >>= 1) {
        if (t < stride) {
#pragma unroll
            for (int bb = 0; bb < BB; bb++) red[bb][t] += red[bb][t + stride];
        }
        __syncthreads();
    }
#pragma unroll
    for (int bb = 0; bb < BB; bb++)
        out[bb * HH + t] = accb[bb] / fmaxf(sqrtf(red[bb][0]), 1e-12f);
}

// ---------------------------------------------------------------------------
extern "C" void kernel_launch(void* const* d_in, const int* in_sizes, int n_in,
                              void* d_out, int out_size, void* d_ws, size_t ws_size,
                              hipStream_t stream) {
    const int*   type_ids = (const int*)d_in[0];   // [B,N]
    const int*   edges    = (const int*)d_in[1];   // [B,E,2]
    const float* emb      = (const float*)d_in[2]; // [V,H]
    const float* w1       = (const float*)d_in[3]; // [H,H]
    const float* b1       = (const float*)d_in[4]; // [H]
    const float* w2       = (const float*)d_in[5]; // [OUT,H]
    const float* b2       = (const float*)d_in[6]; // [OUT]
    float* out = (float*)d_out;                    // [B,OUT] f32

    // Workspace: [zeroed: bits 16MB | deg 256KB | p 64KB | cnt 128B]
    //            [outl 2MB | inl 2MB | embw1 128KB]
    char* ws = (char*)d_ws;
    unsigned long long* bits = (unsigned long long*)ws;
    size_t off = (size_t)BB * NN * WPR * 8;                    // 16 MB
    int2* deg = (int2*)(ws + off);   off += (size_t)BB * NN * 8;
    float* p  = (float*)(ws + off);  off += (size_t)BB * SLICES * HH * 4;
    int* cnt  = (int*)(ws + off);    off += 128;
    size_t zero_bytes = off;
    unsigned short* outl = (unsigned short*)(ws + off); off += (size_t)BB * NN * MAXD * 2;
    unsigned short* inl  = (unsigned short*)(ws + off); off += (size_t)BB * NN * MAXD * 2;
    float* embw1 = (float*)(ws + off);

    hipMemsetAsync(ws, 0, zero_bytes, stream);
    k_scatter_embw1<<<384, 256, 0, stream>>>(edges, emb, w1, bits, deg,
                                             outl, inl, embw1);
    k_fused<<<NBLK_FUSED, 128, 0, stream>>>(type_ids, embw1, deg, outl, inl,
                                            b1, w2, b2, p, cnt, out);
}

// Round 5
// 107.486 us; speedup vs baseline: 2.2670x; 2.2670x over previous
//
#include <hip/hip_runtime.h>
#include <hip/hip_bf16.h>
#include <stdint.h>

// Problem constants
#define BB 8
#define NN 4096
#define NE 8190
#define VV 256
#define HH 128
#define WPR 64      // u64 words per bitmap row (4096 bits)
#define MAXD 32     // unique-degree capacity (Poisson lambda~2, max ~12)
#define SLICES 32   // pool accumulation slices per batch
#define RPB 8       // rows per block in fused kernel

// ---------------------------------------------------------------------------
// K1 (specialized blocks):
//  blocks [0,256): bitmap-dedup edge scatter -> unique out/in lists + degrees
//  blocks [256,384): embW1[v,o] = sum_k emb[v,k]*w1[o,k]  (2 v-rows/block)
// NOTE: plain relaxed atomics only — agent-scope fences cost ~150us on 8-XCD
// gfx950 (R4 post-mortem: threadfence == buffer_wbl2/inv storm).
__global__ void k_scatter_embw1(const int* __restrict__ edges,
                                const float* __restrict__ emb,
                                const float* __restrict__ w1,
                                unsigned long long* __restrict__ bits,
                                int2* __restrict__ deg,
                                unsigned short* __restrict__ outl,
                                unsigned short* __restrict__ inl,
                                float* __restrict__ embw1) {
    int blk = blockIdx.x, t = threadIdx.x;
    if (blk < 256) {
        int idx = blk * 256 + t;
        if (idx >= BB * NE) return;
        int b = idx / NE;
        int src = edges[idx * 2 + 0];
        int dst = edges[idx * 2 + 1];
        int row = b * NN + src;
        unsigned long long m = 1ull << (dst & 63);
        unsigned long long old = atomicOr(&bits[(size_t)row * WPR + (dst >> 6)], m);
        if (!(old & m)) {   // first occurrence owns the unique edge
            int po = atomicAdd(&deg[row].x, 1);
            if (po < MAXD) outl[(size_t)row * MAXD + po] = (unsigned short)dst;
            int col = b * NN + dst;
            int pi = atomicAdd(&deg[col].y, 1);
            if (pi < MAXD) inl[(size_t)col * MAXD + pi] = (unsigned short)src;
        }
    } else {
        __shared__ float er[256];
        int v = (blk - 256) * 2 + (t >> 7);
        int o = t & 127;
        er[t] = emb[v * HH + o];
        __syncthreads();
        const float* erow = &er[(t >> 7) * HH];
        float acc = 0.f;
#pragma unroll 8
        for (int k = 0; k < HH; k++) acc += erow[k] * w1[o * HH + k];
        embw1[v * HH + o] = acc;
    }
}

// ---------------------------------------------------------------------------
// K2: fused SpMM + bias + relu + column-weighted mean-pool accumulation.
//     Exact R2 structure (proven fast). Per row i:
//       dis_i  = rsqrt(outdeg_i + 1)
//       acc_t  = dis_i*embW1[tid_i][t] + sum_{j in out(i)} dis_j*embW1[tid_j][t]
//       h_t    = relu(dis_i*acc_t + b1_t)
//       s_i    = sum_{u in in(i)} dis_u ;  c_i = dis_i*(s_i + dis_i)
//       psum_t += c_i * h_t
//     One sliced atomicAdd per channel at block end. NO fences.
__global__ void __launch_bounds__(128)
k_fused(const int* __restrict__ type_ids,
        const float* __restrict__ embw1,
        const int2* __restrict__ deg,
        const unsigned short* __restrict__ outl,
        const unsigned short* __restrict__ inl,
        const float* __restrict__ b1,
        float* __restrict__ p) {
    __shared__ float djs[MAXD];
    __shared__ int   tjs[MAXD];
    __shared__ float s_sh;
    int t = threadIdx.x;
    int blk = blockIdx.x;
    int base = blk * RPB;
    int b = base >> 12;                   // / NN
    float b1t = b1[t];
    float psum = 0.f;

    for (int r = 0; r < RPB; r++) {
        int row = base + r;
        int2 dg = deg[row];
        int mo = min(dg.x, MAXD);
        int mi = min(dg.y, MAXD);
        // phase A: parallel neighbor-metadata fetch (one latency, not a chain)
        if (t < mo) {
            int gj = b * NN + (int)outl[(size_t)row * MAXD + t];
            djs[t] = rsqrtf((float)(deg[gj].x + 1));
            tjs[t] = type_ids[gj];
        }
        float sloc = 0.f;
        if (t < mi) {
            int gu = b * NN + (int)inl[(size_t)row * MAXD + t];
            sloc = rsqrtf((float)(deg[gu].x + 1));
        }
        // entries live in lanes 0..31 -> 32-wide shuffle reduce on wave 0
        if (t < 64) {
#pragma unroll
            for (int off = 16; off >= 1; off >>= 1)
                sloc += __shfl_down(sloc, off, 32);
            if (t == 0) s_sh = sloc;
        }
        __syncthreads();
        float dis_i = rsqrtf((float)(dg.x + 1));
        float acc = dis_i * embw1[type_ids[row] * HH + t];   // eye term
        for (int q = 0; q < mo; q++)
            acc += djs[q] * embw1[tjs[q] * HH + t];
        float h = fmaxf(dis_i * acc + b1t, 0.f);
        psum += dis_i * (s_sh + dis_i) * h;
        __syncthreads();                    // protect djs/tjs/s_sh
    }
    int slice = blk & (SLICES - 1);
    atomicAdd(&p[((size_t)b * SLICES + slice) * HH + t], psum);
}

// ---------------------------------------------------------------------------
// K3: sum slices, zbar = (pool/N) @ w2^T + b2, L2-normalize.
__global__ void k_final(const float* __restrict__ p,
                        const float* __restrict__ w2,
                        const float* __restrict__ b2,
                        float* __restrict__ out) {
    __shared__ float pl[HH];
    __shared__ float red[HH];
    int b = blockIdx.x, o = threadIdx.x;
    float accp = 0.f;
#pragma unroll 8
    for (int sct = 0; sct < SLICES; sct++)
        accp += p[((size_t)b * SLICES + sct) * HH + o];
    pl[o] = accp * (1.0f / (float)NN);
    __syncthreads();
    float acc = b2[o];
#pragma unroll 8
    for (int k = 0; k < HH; k++) acc += pl[k] * w2[o * HH + k];
    red[o] = acc * acc;
    __syncthreads();
    for (int stride = 64; stride > 0; stride >>= 1) {
        if (o < stride) red[o] += red[o + stride];
        __syncthreads();
    }
    float denom = fmaxf(sqrtf(red[0]), 1e-12f);
    out[b * HH + o] = acc / denom;
}

// ---------------------------------------------------------------------------
extern "C" void kernel_launch(void* const* d_in, const int* in_sizes, int n_in,
                              void* d_out, int out_size, void* d_ws, size_t ws_size,
                              hipStream_t stream) {
    const int*   type_ids = (const int*)d_in[0];   // [B,N]
    const int*   edges    = (const int*)d_in[1];   // [B,E,2]
    const float* emb      = (const float*)d_in[2]; // [V,H]
    const float* w1       = (const float*)d_in[3]; // [H,H]
    const float* b1       = (const float*)d_in[4]; // [H]
    const float* w2       = (const float*)d_in[5]; // [OUT,H]
    const float* b2       = (const float*)d_in[6]; // [OUT]
    float* out = (float*)d_out;                    // [B,OUT] f32

    // Workspace: [zeroed: bits 16MB | deg 256KB | p 128KB]
    //            [outl 2MB | inl 2MB | embw1 128KB]
    char* ws = (char*)d_ws;
    unsigned long long* bits = (unsigned long long*)ws;
    size_t off = (size_t)BB * NN * WPR * 8;                    // 16 MB
    int2* deg = (int2*)(ws + off);   off += (size_t)BB * NN * 8;
    float* p  = (float*)(ws + off);  off += (size_t)BB * SLICES * HH * 4;
    size_t zero_bytes = off;
    unsigned short* outl = (unsigned short*)(ws + off); off += (size_t)BB * NN * MAXD * 2;
    unsigned short* inl  = (unsigned short*)(ws + off); off += (size_t)BB * NN * MAXD * 2;
    float* embw1 = (float*)(ws + off);

    hipMemsetAsync(ws, 0, zero_bytes, stream);
    k_scatter_embw1<<<384, 256, 0, stream>>>(edges, emb, w1, bits, deg,
                                             outl, inl, embw1);
    k_fused<<<BB * NN / RPB, 128, 0, stream>>>(type_ids, embw1, deg, outl, inl,
                                               b1, p);
    k_final<<<BB, HH, 0, stream>>>(p, w2, b2, out);
}